// Round 8
// baseline (1018.689 us; speedup 1.0000x reference)
//
#include <hip/hip_runtime.h>
#include <hip/hip_bf16.h>
#include <math.h>

typedef __hip_bfloat16 bf16;
typedef __attribute__((ext_vector_type(8))) short short8;
typedef __attribute__((ext_vector_type(4))) float f32x4;

#define Bb 8
#define Nn 256
#define Hh 8
#define DEPTHd 4
#define BN 2048
#define RTOT 524288
#define RELB 16384         // RTOT/32 relation blocks
#define JB 64              // BN/32 joint blocks
#define X1S 264            // x1/x2 LDS row stride (bf16)
#define X3S 136
#define XTS 136

__device__ inline float toF(float v) { return v; }
__device__ inline float toF(bf16 v) { return __bfloat162float(v); }
__device__ inline void stF(float* p, float v) { *p = v; }
__device__ inline void stF(bf16* p, float v) { *p = __float2bfloat16(v); }

__device__ inline void gload16(const bf16* g, bf16* l) {
  __builtin_amdgcn_global_load_lds(
      (const __attribute__((address_space(1))) unsigned int*)g,
      (__attribute__((address_space(3))) unsigned int*)l, 16, 0, 0);
}

__device__ inline float blk_sum(float v, float* sred) {
#pragma unroll
  for (int off = 32; off; off >>= 1) v += __shfl_down(v, off, 64);
  int wid = threadIdx.x >> 6;
  int lane = threadIdx.x & 63;
  int nw = blockDim.x >> 6;
  if (lane == 0) sred[wid] = v;
  __syncthreads();
  float s = ((int)threadIdx.x < nw) ? sred[threadIdx.x] : 0.f;
  s += __shfl_down(s, 2, 64);
  s += __shfl_down(s, 1, 64);
  if (threadIdx.x == 0) sred[4] = s;
  __syncthreads();
  float r = sred[4];
  __syncthreads();
  return r;
}

__device__ inline float blk_max(float v, float* sred) {
#pragma unroll
  for (int off = 32; off; off >>= 1) v = fmaxf(v, __shfl_down(v, off, 64));
  int wid = threadIdx.x >> 6;
  int lane = threadIdx.x & 63;
  int nw = blockDim.x >> 6;
  if (lane == 0) sred[wid] = v;
  __syncthreads();
  float s = ((int)threadIdx.x < nw) ? sred[threadIdx.x] : -INFINITY;
  s = fmaxf(s, __shfl_down(s, 2, 64));
  s = fmaxf(s, __shfl_down(s, 1, 64));
  if (threadIdx.x == 0) sred[4] = s;
  __syncthreads();
  float r = sred[4];
  __syncthreads();
  return r;
}

// K=256 loop: A (2 row-tiles) from LDS depth-1, B (NJ col-tiles) from global 3-stage.
template <int NJ>
__device__ __forceinline__ void kloop256(const bf16* xp0, const bf16* xp1,
                                         const bf16* wpa, const bf16* wpb,
                                         const bf16* wpc, const bf16* wpd,
                                         f32x4 (&acc)[2][NJ]) {
  const bf16* wp[4] = {wpa, wpb, wpc, wpd};
  short8 aS[2][2], bS[3][NJ];
  aS[0][0] = *(const short8*)xp0;
  aS[0][1] = *(const short8*)xp1;
#pragma unroll
  for (int j = 0; j < NJ; ++j) {
    bS[0][j] = *(const short8*)(wp[j]);
    bS[1][j] = *(const short8*)(wp[j] + 32);
  }
#pragma unroll
  for (int k = 0; k < 8; ++k) {
    if (k + 1 < 8) {
      aS[(k + 1) & 1][0] = *(const short8*)(xp0 + (k + 1) * 32);
      aS[(k + 1) & 1][1] = *(const short8*)(xp1 + (k + 1) * 32);
    }
    if (k + 2 < 8) {
#pragma unroll
      for (int j = 0; j < NJ; ++j)
        bS[(k + 2) % 3][j] = *(const short8*)(wp[j] + (k + 2) * 32);
    }
#pragma unroll
    for (int i = 0; i < 2; ++i)
#pragma unroll
      for (int j = 0; j < NJ; ++j)
        acc[i][j] = __builtin_amdgcn_mfma_f32_16x16x32_bf16(aS[k & 1][i], bS[k % 3][j],
                                                            acc[i][j], 0, 0, 0);
  }
}

// =============== k_relj: relation encoder (+LN2+rconv->attnR) AND joint encoder ===============
// 32-row blocks. Relation: blocks [0, RELB). Joint: blocks [RELB, RELB+JB) -> jf.
__global__ __launch_bounds__(256, 4) void k_relj(
    const float* __restrict__ rin, const bf16* __restrict__ Wt1,
    const float* __restrict__ b1, const bf16* __restrict__ Wt2,
    const float* __restrict__ b2, const bf16* __restrict__ Wt3,
    const float* __restrict__ b3, const bf16* __restrict__ gWt,
    const float* __restrict__ sgW, const float* __restrict__ bconst,
    bf16* __restrict__ attnR, const float* __restrict__ jin,
    const bf16* __restrict__ Wj1, const float* __restrict__ jb1,
    const bf16* __restrict__ Wj2, const float* __restrict__ jb2,
    const bf16* __restrict__ Wj3, const float* __restrict__ jb3,
    float* __restrict__ jf) {
  __shared__ __align__(16) char smem[35584];
  bf16* x1 = (bf16*)smem;                    // [32][264]
  bf16* x2 = (bf16*)(smem + 16896);          // [32][264]
  bf16* x3 = x1;                             // [32][136]
  float* sstat = (float*)(smem + 33792);     // [32][4][2]
  float* sstatF = (float*)(smem + 34816);    // [32][2]
  bf16* sA0 = x2;                            // staging: rel [32][40], joint [32][104]

  const int t = threadIdx.x;
  const int lane = t & 63, wv = t >> 6;
  const int lrow = lane & 15, quad = lane >> 4;
  const bool rel = blockIdx.x < RELB;

  const bf16* W2 = rel ? Wt2 : Wj2;
  const bf16* W3 = rel ? Wt3 : Wj3;
  const float* bb2 = rel ? b2 : jb2;

  if (rel) {
    const long r0 = (long)blockIdx.x * 32;
    // stage rin [32][26] f32 -> sA0 bf16 [32][40-stride]
    for (int idx = t; idx < 32 * 32; idx += 256) {
      int r = idx >> 5, k = idx & 31;
      sA0[r * 40 + k] = __float2bfloat16(k < 26 ? rin[(r0 + r) * 26 + k] : 0.f);
    }
    __syncthreads();
    // L1: K=32
    {
      short8 af[2], bw[4];
#pragma unroll
      for (int i = 0; i < 2; ++i)
        af[i] = *(const short8*)&sA0[(i * 16 + lrow) * 40 + quad * 8];
#pragma unroll
      for (int j = 0; j < 4; ++j)
        bw[j] = *(const short8*)&Wt1[(wv * 64 + j * 16 + lrow) * 32 + quad * 8];
      f32x4 acc[2][4];
#pragma unroll
      for (int i = 0; i < 2; ++i)
#pragma unroll
        for (int j = 0; j < 4; ++j) {
          f32x4 z = {0.f, 0.f, 0.f, 0.f};
          acc[i][j] = __builtin_amdgcn_mfma_f32_16x16x32_bf16(af[i], bw[j], z, 0, 0, 0);
        }
      __syncthreads();  // sA0 reads done (x2 alias), before x1 write races? x1 disjoint; barrier guards sA0 vs later x2 writes
#pragma unroll
      for (int i = 0; i < 2; ++i)
#pragma unroll
        for (int j = 0; j < 4; ++j) {
          int col = wv * 64 + j * 16 + lrow;
          float bv = b1[col];
#pragma unroll
          for (int r = 0; r < 4; ++r)
            x1[(i * 16 + quad * 4 + r) * X1S + col] = __float2bfloat16(acc[i][j][r] + bv);
        }
    }
  } else {
    const long r0j = (long)(blockIdx.x - RELB) * 32;
    // stage joint_in [32][96] f32 -> sA0 bf16 [32][104-stride]
    for (int idx = t; idx < 32 * 96; idx += 256) {
      int r = idx / 96, k = idx - r * 96;
      sA0[r * 104 + k] = __float2bfloat16(jin[(r0j + r) * 96 + k]);
    }
    __syncthreads();
    // L1: K=96
    {
      f32x4 acc[2][4];
#pragma unroll
      for (int i = 0; i < 2; ++i)
#pragma unroll
        for (int j = 0; j < 4; ++j) {
          f32x4 z = {0.f, 0.f, 0.f, 0.f};
          acc[i][j] = z;
        }
#pragma unroll
      for (int kt = 0; kt < 3; ++kt) {
        short8 af[2], bw[4];
#pragma unroll
        for (int i = 0; i < 2; ++i)
          af[i] = *(const short8*)&sA0[(i * 16 + lrow) * 104 + kt * 32 + quad * 8];
#pragma unroll
        for (int j = 0; j < 4; ++j)
          bw[j] = *(const short8*)&Wj1[(wv * 64 + j * 16 + lrow) * 96 + kt * 32 + quad * 8];
#pragma unroll
        for (int i = 0; i < 2; ++i)
#pragma unroll
          for (int j = 0; j < 4; ++j)
            acc[i][j] =
                __builtin_amdgcn_mfma_f32_16x16x32_bf16(af[i], bw[j], acc[i][j], 0, 0, 0);
      }
      __syncthreads();
#pragma unroll
      for (int i = 0; i < 2; ++i)
#pragma unroll
        for (int j = 0; j < 4; ++j) {
          int col = wv * 64 + j * 16 + lrow;
          float bv = jb1[col];
#pragma unroll
          for (int r = 0; r < 4; ++r)
            x1[(i * 16 + quad * 4 + r) * X1S + col] = __float2bfloat16(acc[i][j][r] + bv);
        }
    }
  }
  __syncthreads();

  // ---- L2: x2 = x1 @ W2^T + bb2 (K=256) ----
  {
    f32x4 acc[2][4];
#pragma unroll
    for (int i = 0; i < 2; ++i)
#pragma unroll
      for (int j = 0; j < 4; ++j) {
        f32x4 z = {0.f, 0.f, 0.f, 0.f};
        acc[i][j] = z;
      }
    const bf16* xp0 = &x1[lrow * X1S + quad * 8];
    const bf16* xp1 = &x1[(16 + lrow) * X1S + quad * 8];
    kloop256<4>(xp0, xp1, &W2[(wv * 64 + lrow) * 256 + quad * 8],
                &W2[(wv * 64 + 16 + lrow) * 256 + quad * 8],
                &W2[(wv * 64 + 32 + lrow) * 256 + quad * 8],
                &W2[(wv * 64 + 48 + lrow) * 256 + quad * 8], acc);
#pragma unroll
    for (int i = 0; i < 2; ++i)
#pragma unroll
      for (int j = 0; j < 4; ++j) {
        int col = wv * 64 + j * 16 + lrow;
        float bv = bb2[col];
#pragma unroll
        for (int r = 0; r < 4; ++r)
          x2[(i * 16 + quad * 4 + r) * X1S + col] = __float2bfloat16(acc[i][j][r] + bv);
      }
  }
  __syncthreads();

  // ---- L3: K=256, 128 cols (wave strip wv*32), 2 row-tiles x 2 col-tiles ----
  {
    f32x4 acc[2][2];
#pragma unroll
    for (int i = 0; i < 2; ++i) {
      f32x4 z = {0.f, 0.f, 0.f, 0.f};
      acc[i][0] = z;
      acc[i][1] = z;
    }
    const bf16* xp0 = &x2[lrow * X1S + quad * 8];
    const bf16* xp1 = &x2[(16 + lrow) * X1S + quad * 8];
    const bf16* w0 = &W3[(wv * 32 + lrow) * 256 + quad * 8];
    const bf16* w1 = &W3[(wv * 32 + 16 + lrow) * 256 + quad * 8];
    kloop256<2>(xp0, xp1, w0, w1, w0, w1, acc);

    if (rel) {
      const float* bb3 = b3;
#pragma unroll
      for (int i = 0; i < 2; ++i) {
#pragma unroll
        for (int r = 0; r < 4; ++r) {
          int row = i * 16 + quad * 4 + r;
          float v0 = acc[i][0][r] + bb3[wv * 32 + lrow];
          float v1 = acc[i][1][r] + bb3[wv * 32 + 16 + lrow];
          x3[row * X3S + wv * 32 + lrow] = __float2bfloat16(v0);
          x3[row * X3S + wv * 32 + 16 + lrow] = __float2bfloat16(v1);
          float s1 = v0 + v1, s2 = v0 * v0 + v1 * v1;
#pragma unroll
          for (int m = 1; m < 16; m <<= 1) {
            s1 += __shfl_xor(s1, m, 64);
            s2 += __shfl_xor(s2, m, 64);
          }
          if (lrow == 0) {
            sstat[(row * 4 + wv) * 2] = s1;
            sstat[(row * 4 + wv) * 2 + 1] = s2;
          }
        }
      }
    } else {
      const long r0j = (long)(blockIdx.x - RELB) * 32;
#pragma unroll
      for (int i = 0; i < 2; ++i) {
#pragma unroll
        for (int j = 0; j < 2; ++j) {
          int col = wv * 32 + j * 16 + lrow;
          float bv = jb3[col];
#pragma unroll
          for (int r = 0; r < 4; ++r) {
            int row = i * 16 + quad * 4 + r;
            jf[(r0j + row) * 128 + col] = acc[i][j][r] + bv;
          }
        }
      }
      return;  // joint blocks done
    }
  }
  // hoist gemm32 A-operands while barriers drain
  const int colt = wv >> 1, rowt = wv & 1;
  short8 aw[4];
#pragma unroll
  for (int kk = 0; kk < 4; ++kk)
    aw[kk] = *(const short8*)&gWt[(colt * 16 + lrow) * 128 + kk * 32 + quad * 8];
  __syncthreads();
  if (t < 32) {
    float s1 = 0.f, s2 = 0.f;
#pragma unroll
    for (int w = 0; w < 4; ++w) {
      s1 += sstat[(t * 4 + w) * 2];
      s2 += sstat[(t * 4 + w) * 2 + 1];
    }
    float mu = s1 * (1.f / 128.f);
    float var = s2 * (1.f / 128.f) - mu * mu;
    sstatF[t * 2] = mu;
    sstatF[t * 2 + 1] = rsqrtf(var + 1e-5f);
  }
  __syncthreads();

  // ---- gemm32: wave = (colt, rowt) 16x16 tile; LN stats trick; scatter ----
  {
    f32x4 acc2 = {0.f, 0.f, 0.f, 0.f};
#pragma unroll
    for (int kk = 0; kk < 4; ++kk) {
      short8 bbx = *(const short8*)&x3[(rowt * 16 + lrow) * X3S + kk * 32 + quad * 8];
      acc2 = __builtin_amdgcn_mfma_f32_16x16x32_bf16(aw[kk], bbx, acc2, 0, 0, 0);
    }
    const long r0 = (long)blockIdx.x * 32;
    int drow = rowt * 16 + lrow;
    long gr = r0 + drow;
    float mu = sstatF[drow * 2], inv = sstatF[drow * 2 + 1];
    int bb_ = (int)(gr >> 16);
    int nn = (int)((gr >> 8) & 255);
    int mm = (int)(gr & 255);
#pragma unroll
    for (int reg = 0; reg < 4; ++reg) {
      int col = colt * 16 + quad * 4 + reg;
      float v = inv * (acc2[reg] - mu * sgW[col]) + bconst[col];
      int dd = col >> 3, hh = col & 7;
      attnR[((((long)dd * Bb + bb_) * Hh + hh) * Nn + nn) * Nn + mm] =
          __float2bfloat16(v);
    }
  }
}

// =============== MFMA GEMM (generic, LDS-staged): decoder 2/3 ===============
template <typename TA, typename TC, bool GELU, bool RESID>
__global__ __launch_bounds__(256) void k_gemm_mfma(
    const TA* __restrict__ A, int Ka, int Kp, const bf16* __restrict__ Bt,
    const float* __restrict__ bias, TC* __restrict__ C, int ldc, int ncols,
    const float* __restrict__ resid) {
  __shared__ __align__(16) bf16 sA[128 * 32];
  __shared__ __align__(16) bf16 sB[128 * 32];
  const int t = threadIdx.x;
  const int lane = t & 63;
  const int wv = t >> 6;
  const int wr = wv >> 1, wc = wv & 1;
  const int lrow = lane & 15, quad = lane >> 4;
  const long row0 = (long)blockIdx.y * 128;
  const int n0 = blockIdx.x * 128;
  const int rg = lane >> 2;
  const int kE = (lane & 3) * 8;

  f32x4 zero = {0.f, 0.f, 0.f, 0.f};
  f32x4 acc[4][4];
#pragma unroll
  for (int i = 0; i < 4; ++i)
#pragma unroll
    for (int j = 0; j < 4; ++j) acc[i][j] = zero;

  for (int k0 = 0; k0 < Kp; k0 += 32) {
    {
      const int r0 = wv * 32;
      gload16(&Bt[(long)(n0 + r0 + rg) * Kp + k0 + kE], &sB[r0 * 32]);
      gload16(&Bt[(long)(n0 + r0 + 16 + rg) * Kp + k0 + kE], &sB[(r0 + 16) * 32]);
    }
    if (sizeof(TA) == 2) {
      const int r0 = wv * 32;
      gload16((const bf16*)&A[(row0 + r0 + rg) * (long)Ka + k0 + kE], &sA[r0 * 32]);
      gload16((const bf16*)&A[(row0 + r0 + 16 + rg) * (long)Ka + k0 + kE],
              &sA[(r0 + 16) * 32]);
    } else {
      for (int idx = t; idx < 128 * 32; idx += 256) {
        int r = idx >> 5, k = idx & 31;
        int gk = k0 + k;
        float v = (gk < Ka) ? toF(A[(row0 + r) * (long)Ka + gk]) : 0.f;
        sA[idx] = __float2bfloat16(v);
      }
    }
    __syncthreads();
    short8 af[4], bfr[4];
#pragma unroll
    for (int i = 0; i < 4; ++i)
      af[i] = *(const short8*)&sA[(wr * 64 + i * 16 + lrow) * 32 + quad * 8];
#pragma unroll
    for (int j = 0; j < 4; ++j)
      bfr[j] = *(const short8*)&sB[(wc * 64 + j * 16 + lrow) * 32 + quad * 8];
#pragma unroll
    for (int i = 0; i < 4; ++i)
#pragma unroll
      for (int j = 0; j < 4; ++j)
        acc[i][j] =
            __builtin_amdgcn_mfma_f32_16x16x32_bf16(af[i], bfr[j], acc[i][j], 0, 0, 0);
    __syncthreads();
  }

#pragma unroll
  for (int i = 0; i < 4; ++i) {
#pragma unroll
    for (int r = 0; r < 4; ++r) {
      int rl = wr * 64 + i * 16 + quad * 4 + r;
      long gr = row0 + rl;
#pragma unroll
      for (int j = 0; j < 4; ++j) {
        int gc = n0 + wc * 64 + j * 16 + lrow;
        if (gc < ncols) {
          float v = acc[i][j][r] + bias[gc];
          if (GELU) v = 0.5f * v * (1.f + erff(v * 0.70710678118654752f));
          if (RESID) v += resid[gr * (long)ldc + gc];
          stF(&C[gr * (long)ldc + gc], v);
        }
      }
    }
  }
}

// =============== k_lnqkv: row-LN (dim 128) fused into K=128 GEMM ===============
template <typename TC>
__global__ __launch_bounds__(256) void k_lnqkv(
    const float* __restrict__ A, const float* __restrict__ g,
    const float* __restrict__ b, const bf16* __restrict__ Bt,
    const float* __restrict__ bias, TC* __restrict__ C, int ldc, int ncols) {
  __shared__ __align__(16) bf16 sX[128 * XTS];
  const int t = threadIdx.x;
  const int lane = t & 63;
  const int wv = t >> 6;
  const int wr = wv >> 1, wc = wv & 1;
  const int lrow = lane & 15, quad = lane >> 4;
  const long row0 = (long)blockIdx.y * 128;
  const int n0 = blockIdx.x * 128;

  {
    int row = t >> 1, half = t & 1;
    const float* ap = &A[(row0 + row) * 128 + half * 64];
    float v[64];
    float s1 = 0.f, s2 = 0.f;
#pragma unroll
    for (int u = 0; u < 16; ++u) {
      f32x4 q = *(const f32x4*)(ap + u * 4);
#pragma unroll
      for (int e = 0; e < 4; ++e) {
        v[u * 4 + e] = q[e];
        s1 += q[e];
        s2 += q[e] * q[e];
      }
    }
    s1 += __shfl_xor(s1, 1, 64);
    s2 += __shfl_xor(s2, 1, 64);
    float mu = s1 * (1.f / 128.f);
    float inv = rsqrtf(s2 * (1.f / 128.f) - mu * mu + 1e-5f);
#pragma unroll
    for (int u = 0; u < 64; ++u) {
      int c = half * 64 + u;
      sX[row * XTS + c] = __float2bfloat16((v[u] - mu) * inv * g[c] + b[c]);
    }
  }
  __syncthreads();

  f32x4 acc[4][4];
#pragma unroll
  for (int i = 0; i < 4; ++i)
#pragma unroll
    for (int j = 0; j < 4; ++j) {
      f32x4 z = {0.f, 0.f, 0.f, 0.f};
      acc[i][j] = z;
    }
#pragma unroll
  for (int k0 = 0; k0 < 128; k0 += 32) {
    short8 af[4], bfr[4];
#pragma unroll
    for (int j = 0; j < 4; ++j)
      bfr[j] = *(const short8*)&Bt[(long)(n0 + wc * 64 + j * 16 + lrow) * 128 + k0 +
                                   quad * 8];
#pragma unroll
    for (int i = 0; i < 4; ++i)
      af[i] = *(const short8*)&sX[(wr * 64 + i * 16 + lrow) * XTS + k0 + quad * 8];
#pragma unroll
    for (int i = 0; i < 4; ++i)
#pragma unroll
      for (int j = 0; j < 4; ++j)
        acc[i][j] =
            __builtin_amdgcn_mfma_f32_16x16x32_bf16(af[i], bfr[j], acc[i][j], 0, 0, 0);
  }
#pragma unroll
  for (int i = 0; i < 4; ++i) {
#pragma unroll
    for (int r = 0; r < 4; ++r) {
      long gr = row0 + wr * 64 + i * 16 + quad * 4 + r;
#pragma unroll
      for (int j = 0; j < 4; ++j) {
        int gc = n0 + wc * 64 + j * 16 + lrow;
        if (gc < ncols) stF(&C[gr * (long)ldc + gc], acc[i][j][r] + bias[gc]);
      }
    }
  }
}

// =============== k_tailq: proj+resid -> LN3 -> MLP(+gelu) -> resid [-> LN1' + QKV'] ===============
template <bool QKV>
__global__ __launch_bounds__(256) void k_tailq(
    const bf16* __restrict__ obuf, float* __restrict__ jf, const bf16* __restrict__ Wp,
    const float* __restrict__ pb, const float* __restrict__ g3,
    const float* __restrict__ b3, const bf16* __restrict__ Wm1,
    const float* __restrict__ m1b, const bf16* __restrict__ Wm2,
    const float* __restrict__ m2b, const float* __restrict__ g1n,
    const float* __restrict__ b1n, const bf16* __restrict__ Wqn,
    const float* __restrict__ qbn, float* __restrict__ qkvb) {
  __shared__ __align__(16) bf16 sX[128 * XTS];
  __shared__ __align__(16) bf16 sH[128 * XTS];
  __shared__ float sstat[128][2][2];
  __shared__ float sstatF[128][2];

  const int t = threadIdx.x;
  const int lane = t & 63;
  const int wv = t >> 6;
  const int wr = wv >> 1, wc = wv & 1;
  const int lrow = lane & 15, quad = lane >> 4;
  const long row0 = (long)blockIdx.x * 128;

#pragma unroll
  for (int u = 0; u < 8; ++u) {
    int idx = t + u * 256;
    int r = idx >> 4, c8 = (idx & 15) * 8;
    *(uint4*)&sX[r * XTS + c8] = *(const uint4*)&obuf[(row0 + r) * 128 + c8];
  }
  __syncthreads();

  f32x4 acc[4][4];
#pragma unroll
  for (int i = 0; i < 4; ++i)
#pragma unroll
    for (int j = 0; j < 4; ++j) {
      f32x4 z = {0.f, 0.f, 0.f, 0.f};
      acc[i][j] = z;
    }
#pragma unroll
  for (int k0 = 0; k0 < 128; k0 += 32) {
    short8 af[4], bfr[4];
#pragma unroll
    for (int i = 0; i < 4; ++i)
      af[i] = *(const short8*)&sX[(wr * 64 + i * 16 + lrow) * XTS + k0 + quad * 8];
#pragma unroll
    for (int j = 0; j < 4; ++j)
      bfr[j] = *(const short8*)&Wp[(wc * 64 + j * 16 + lrow) * 128 + k0 + quad * 8];
#pragma unroll
    for (int i = 0; i < 4; ++i)
#pragma unroll
      for (int j = 0; j < 4; ++j)
        acc[i][j] =
            __builtin_amdgcn_mfma_f32_16x16x32_bf16(af[i], bfr[j], acc[i][j], 0, 0, 0);
  }
#pragma unroll
  for (int i = 0; i < 4; ++i) {
#pragma unroll
    for (int r = 0; r < 4; ++r) {
      int rl = wr * 64 + i * 16 + quad * 4 + r;
      long gr = row0 + rl;
      float s1 = 0.f, s2 = 0.f;
#pragma unroll
      for (int j = 0; j < 4; ++j) {
        int gc = wc * 64 + j * 16 + lrow;
        float v = acc[i][j][r] + pb[gc] + jf[gr * 128 + gc];
        acc[i][j][r] = v;
        jf[gr * 128 + gc] = v;
        s1 += v;
        s2 += v * v;
      }
#pragma unroll
      for (int m = 1; m < 16; m <<= 1) {
        s1 += __shfl_xor(s1, m, 64);
        s2 += __shfl_xor(s2, m, 64);
      }
      if (lrow == 0) {
        sstat[rl][wc][0] = s1;
        sstat[rl][wc][1] = s2;
      }
    }
  }
  __syncthreads();
  if (t < 128) {
    float s1 = sstat[t][0][0] + sstat[t][1][0];
    float s2 = sstat[t][0][1] + sstat[t][1][1];
    float mu = s1 * (1.f / 128.f);
    float var = s2 * (1.f / 128.f) - mu * mu;
    sstatF[t][0] = mu;
    sstatF[t][1] = rsqrtf(var + 1e-5f);
  }
  __syncthreads();
#pragma unroll
  for (int i = 0; i < 4; ++i) {
#pragma unroll
    for (int r = 0; r < 4; ++r) {
      int rl = wr * 64 + i * 16 + quad * 4 + r;
      float mu = sstatF[rl][0], inv = sstatF[rl][1];
#pragma unroll
      for (int j = 0; j < 4; ++j) {
        int gc = wc * 64 + j * 16 + lrow;
        sX[rl * XTS + gc] = __float2bfloat16((acc[i][j][r] - mu) * inv * g3[gc] + b3[gc]);
      }
    }
  }
  __syncthreads();

  // GEMM2: h = gelu(x @ Wm1 + m1b)
  f32x4 acc2[4][4];
#pragma unroll
  for (int i = 0; i < 4; ++i)
#pragma unroll
    for (int j = 0; j < 4; ++j) {
      f32x4 z = {0.f, 0.f, 0.f, 0.f};
      acc2[i][j] = z;
    }
#pragma unroll
  for (int k0 = 0; k0 < 128; k0 += 32) {
    short8 af[4], bfr[4];
#pragma unroll
    for (int i = 0; i < 4; ++i)
      af[i] = *(const short8*)&sX[(wr * 64 + i * 16 + lrow) * XTS + k0 + quad * 8];
#pragma unroll
    for (int j = 0; j < 4; ++j)
      bfr[j] = *(const short8*)&Wm1[(wc * 64 + j * 16 + lrow) * 128 + k0 + quad * 8];
#pragma unroll
    for (int i = 0; i < 4; ++i)
#pragma unroll
      for (int j = 0; j < 4; ++j)
        acc2[i][j] =
            __builtin_amdgcn_mfma_f32_16x16x32_bf16(af[i], bfr[j], acc2[i][j], 0, 0, 0);
  }
#pragma unroll
  for (int i = 0; i < 4; ++i) {
#pragma unroll
    for (int r = 0; r < 4; ++r) {
      int rl = wr * 64 + i * 16 + quad * 4 + r;
#pragma unroll
      for (int j = 0; j < 4; ++j) {
        int gc = wc * 64 + j * 16 + lrow;
        float v = acc2[i][j][r] + m1b[gc];
        v = 0.5f * v * (1.f + erff(v * 0.70710678118654752f));
        sH[rl * XTS + gc] = __float2bfloat16(v);
      }
    }
  }
  __syncthreads();

  // GEMM3: jf = h @ Wm2 + m2b + jf_new
  f32x4 acc3[4][4];
#pragma unroll
  for (int i = 0; i < 4; ++i)
#pragma unroll
    for (int j = 0; j < 4; ++j) {
      f32x4 z = {0.f, 0.f, 0.f, 0.f};
      acc3[i][j] = z;
    }
#pragma unroll
  for (int k0 = 0; k0 < 128; k0 += 32) {
    short8 af[4], bfr[4];
#pragma unroll
    for (int i = 0; i < 4; ++i)
      af[i] = *(const short8*)&sH[(wr * 64 + i * 16 + lrow) * XTS + k0 + quad * 8];
#pragma unroll
    for (int j = 0; j < 4; ++j)
      bfr[j] = *(const short8*)&Wm2[(wc * 64 + j * 16 + lrow) * 128 + k0 + quad * 8];
#pragma unroll
    for (int i = 0; i < 4; ++i)
#pragma unroll
      for (int j = 0; j < 4; ++j)
        acc3[i][j] =
            __builtin_amdgcn_mfma_f32_16x16x32_bf16(af[i], bfr[j], acc3[i][j], 0, 0, 0);
  }
#pragma unroll
  for (int i = 0; i < 4; ++i) {
#pragma unroll
    for (int r = 0; r < 4; ++r) {
      int rl = wr * 64 + i * 16 + quad * 4 + r;
      long gr = row0 + rl;
      float s1 = 0.f, s2 = 0.f;
#pragma unroll
      for (int j = 0; j < 4; ++j) {
        int gc = wc * 64 + j * 16 + lrow;
        float v = acc3[i][j][r] + m2b[gc] + jf[gr * 128 + gc];
        acc3[i][j][r] = v;
        jf[gr * 128 + gc] = v;
        if (QKV) {
          s1 += v;
          s2 += v * v;
        }
      }
      if (QKV) {
#pragma unroll
        for (int m = 1; m < 16; m <<= 1) {
          s1 += __shfl_xor(s1, m, 64);
          s2 += __shfl_xor(s2, m, 64);
        }
        if (lrow == 0) {
          sstat[rl][wc][0] = s1;
          sstat[rl][wc][1] = s2;
        }
      }
    }
  }
  if (!QKV) return;
  __syncthreads();
  if (t < 128) {
    float s1 = sstat[t][0][0] + sstat[t][1][0];
    float s2 = sstat[t][0][1] + sstat[t][1][1];
    float mu = s1 * (1.f / 128.f);
    float var = s2 * (1.f / 128.f) - mu * mu;
    sstatF[t][0] = mu;
    sstatF[t][1] = rsqrtf(var + 1e-5f);
  }
  __syncthreads();
#pragma unroll
  for (int i = 0; i < 4; ++i) {
#pragma unroll
    for (int r = 0; r < 4; ++r) {
      int rl = wr * 64 + i * 16 + quad * 4 + r;
      float mu = sstatF[rl][0], inv = sstatF[rl][1];
#pragma unroll
      for (int j = 0; j < 4; ++j) {
        int gc = wc * 64 + j * 16 + lrow;
        sX[rl * XTS + gc] =
            __float2bfloat16((acc3[i][j][r] - mu) * inv * g1n[gc] + b1n[gc]);
      }
    }
  }
  __syncthreads();
  // QKV for next depth: 3 col passes of 128
  for (int p = 0; p < 3; ++p) {
    f32x4 acc4[4][4];
#pragma unroll
    for (int i = 0; i < 4; ++i)
#pragma unroll
      for (int j = 0; j < 4; ++j) {
        f32x4 z = {0.f, 0.f, 0.f, 0.f};
        acc4[i][j] = z;
      }
#pragma unroll
    for (int k0 = 0; k0 < 128; k0 += 32) {
      short8 af[4], bfr[4];
#pragma unroll
      for (int i = 0; i < 4; ++i)
        af[i] = *(const short8*)&sX[(wr * 64 + i * 16 + lrow) * XTS + k0 + quad * 8];
#pragma unroll
      for (int j = 0; j < 4; ++j)
        bfr[j] = *(const short8*)&Wqn[(long)(p * 128 + wc * 64 + j * 16 + lrow) * 128 +
                                      k0 + quad * 8];
#pragma unroll
      for (int i = 0; i < 4; ++i)
#pragma unroll
        for (int j = 0; j < 4; ++j)
          acc4[i][j] =
              __builtin_amdgcn_mfma_f32_16x16x32_bf16(af[i], bfr[j], acc4[i][j], 0, 0, 0);
    }
#pragma unroll
    for (int i = 0; i < 4; ++i) {
#pragma unroll
      for (int r = 0; r < 4; ++r) {
        long gr = row0 + wr * 64 + i * 16 + quad * 4 + r;
#pragma unroll
        for (int j = 0; j < 4; ++j) {
          int gc = p * 128 + wc * 64 + j * 16 + lrow;
          qkvb[gr * 384 + gc] = acc4[i][j][r] + qbn[gc];
        }
      }
    }
  }
}

// ---- prep: transpose+cast all weights to bf16 [col][K]; build gW / sgW / bconst ----
__global__ void k_prep(const float* re_w1, const float* re_w2, const float* re_w3,
                       const float* ln2_g, const float* ln2_b, const float* rconv_w,
                       const float* rconv_b, const float* je_w1, const float* je_w2,
                       const float* je_w3, const float* qkv_w, const float* proj_w,
                       const float* mw1, const float* mw2, const float* dw1,
                       const float* dw2, const float* dw3, bf16* Wt1, bf16* Wt2,
                       bf16* Wt3, bf16* gWt, float* sgW, float* bconst, bf16* Wj1,
                       bf16* Wj2, bf16* Wj3, bf16* Wq, bf16* Wp, bf16* Wm1, bf16* Wm2,
                       bf16* Wd1, bf16* Wd2, bf16* Wd3) {
  const int stride = gridDim.x * blockDim.x;
  const int tid = blockIdx.x * blockDim.x + threadIdx.x;
  for (int i = tid; i < 256 * 32; i += stride) {
    int n = i >> 5, k = i & 31;
    Wt1[i] = __float2bfloat16(k < 26 ? re_w1[k * 256 + n] : 0.f);
  }
  for (int i = tid; i < 256 * 256; i += stride) {
    int n = i >> 8, k = i & 255;
    Wt2[i] = __float2bfloat16(re_w2[k * 256 + n]);
  }
  for (int i = tid; i < 128 * 256; i += stride) {
    int n = i >> 8, k = i & 255;
    Wt3[i] = __float2bfloat16(re_w3[k * 128 + n]);
  }
  for (int i = tid; i < 32 * 128; i += stride) {
    int col = i >> 7, c = i & 127;
    int dd = col >> 3, h = col & 7;
    gWt[i] = __float2bfloat16(ln2_g[dd * 128 + c] * rconv_w[(dd * 128 + c) * 8 + h]);
  }
  if (tid < 32) {
    int dd = tid >> 3, h = tid & 7;
    float sg = 0.f, bc = 0.f;
    for (int c = 0; c < 128; ++c) {
      float w = rconv_w[(dd * 128 + c) * 8 + h];
      sg += ln2_g[dd * 128 + c] * w;
      bc += ln2_b[dd * 128 + c] * w;
    }
    sgW[tid] = sg;
    bconst[tid] = bc + rconv_b[tid];
  }
  for (int i = tid; i < 256 * 96; i += stride) {
    int n = i / 96, k = i - n * 96;
    Wj1[i] = __float2bfloat16(je_w1[k * 256 + n]);
  }
  for (int i = tid; i < 256 * 256; i += stride) {
    int n = i >> 8, k = i & 255;
    Wj2[i] = __float2bfloat16(je_w2[k * 256 + n]);
  }
  for (int i = tid; i < 128 * 256; i += stride) {
    int n = i >> 8, k = i & 255;
    Wj3[i] = __float2bfloat16(je_w3[k * 128 + n]);
  }
  for (int i = tid; i < 4 * 384 * 128; i += stride) {
    int d = i / 49152, rem = i - d * 49152;
    int n = rem >> 7, k = rem & 127;
    Wq[i] = __float2bfloat16(qkv_w[d * 49152 + k * 384 + n]);
  }
  for (int i = tid; i < 4 * 128 * 128; i += stride) {
    int d = i >> 14, rem = i & 16383;
    int n = rem >> 7, k = rem & 127;
    Wp[i] = __float2bfloat16(proj_w[d * 16384 + k * 128 + n]);
    Wm1[i] = __float2bfloat16(mw1[d * 16384 + k * 128 + n]);
    Wm2[i] = __float2bfloat16(mw2[d * 16384 + k * 128 + n]);
  }
  for (int i = tid; i < 256 * 128; i += stride) {
    int n = i >> 7, k = i & 127;
    Wd1[i] = __float2bfloat16(dw1[k * 256 + n]);
  }
  for (int i = tid; i < 512 * 256; i += stride) {
    int n = i >> 8, k = i & 255;
    Wd2[i] = __float2bfloat16(dw2[k * 512 + n]);
  }
  for (int i = tid; i < 128 * 512; i += stride) {
    int n = i >> 9, k = i & 511;
    Wd3[i] = __float2bfloat16(n < 90 ? dw3[k * 90 + n] : 0.f);
  }
}

// ---- fused attention: logits + conn + softmax + AV ----
__global__ void k_attn(const float* __restrict__ qkv, const bf16* __restrict__ aR,
                       const float* __restrict__ conn, bf16* __restrict__ obuf) {
  __shared__ float q[16];
  __shared__ float p[256];
  __shared__ float sred[8];
  __shared__ float pv[16][17];
  int n = blockIdx.x, h = blockIdx.y, b = blockIdx.z;
  int t = threadIdx.x;
  if (t < 16) q[t] = qkv[((long)(b * Nn + n)) * 384 + h * 16 + t];
  __syncthreads();
  const float* kp = &qkv[((long)(b * Nn + t)) * 384 + 128 + h * 16];
  float lg = 0.f;
#pragma unroll
  for (int e = 0; e < 16; ++e) lg += q[e] * kp[e];
  lg += toF(aR[(((long)(b * Hh + h) * Nn + n)) * Nn + t]);
  lg = lg * conn[((long)(b * Nn + n)) * Nn + t] * 0.25f;
  float mx = blk_max(lg, sred);
  float ex = expf(lg - mx);
  float s = blk_sum(ex, sred);
  p[t] = ex / s;
  __syncthreads();
  int g = t >> 4, e = t & 15;
  const float* vp = &qkv[((long)(b * Nn + g * 16)) * 384 + 256 + h * 16 + e];
  float acc = 0.f;
#pragma unroll
  for (int mi = 0; mi < 16; ++mi) acc += p[g * 16 + mi] * vp[(long)mi * 384];
  pv[g][e] = acc;
  __syncthreads();
  if (t < 16) {
    float s2 = 0.f;
#pragma unroll
    for (int gg = 0; gg < 16; ++gg) s2 += pv[gg][t];
    obuf[((long)(b * Nn + n)) * 128 + h * 16 + t] = __float2bfloat16(s2);
  }
}

extern "C" void kernel_launch(void* const* d_in, const int* in_sizes, int n_in,
                              void* d_out, int out_size, void* d_ws, size_t ws_size,
                              hipStream_t stream) {
  const float* joint_in = (const float*)d_in[0];
  const float* relation_in = (const float*)d_in[1];
  const float* conn = (const float*)d_in[2];
  const float* je_w1 = (const float*)d_in[3];
  const float* je_b1 = (const float*)d_in[4];
  const float* je_w2 = (const float*)d_in[5];
  const float* je_b2 = (const float*)d_in[6];
  const float* je_w3 = (const float*)d_in[7];
  const float* je_b3 = (const float*)d_in[8];
  const float* re_w1 = (const float*)d_in[9];
  const float* re_b1 = (const float*)d_in[10];
  const float* re_w2 = (const float*)d_in[11];
  const float* re_b2 = (const float*)d_in[12];
  const float* re_w3 = (const float*)d_in[13];
  const float* re_b3 = (const float*)d_in[14];
  const float* qkv_w = (const float*)d_in[15];
  const float* qkv_b = (const float*)d_in[16];
  const float* rconv_w = (const float*)d_in[17];
  const float* rconv_b = (const float*)d_in[18];
  const float* proj_w = (const float*)d_in[19];
  const float* proj_b = (const float*)d_in[20];
  const float* ln1_g = (const float*)d_in[21];
  const float* ln1_b = (const float*)d_in[22];
  const float* ln2_g = (const float*)d_in[23];
  const float* ln2_b = (const float*)d_in[24];
  const float* ln3_g = (const float*)d_in[25];
  const float* ln3_b = (const float*)d_in[26];
  const float* mw1 = (const float*)d_in[27];
  const float* mb1 = (const float*)d_in[28];
  const float* mw2 = (const float*)d_in[29];
  const float* mb2 = (const float*)d_in[30];
  const float* ng = (const float*)d_in[31];
  const float* nb = (const float*)d_in[32];
  const float* dw1 = (const float*)d_in[33];
  const float* db1 = (const float*)d_in[34];
  const float* dw2 = (const float*)d_in[35];
  const float* db2 = (const float*)d_in[36];
  const float* dw3 = (const float*)d_in[37];
  const float* db3 = (const float*)d_in[38];

  char* ws = (char*)d_ws;
  size_t off = 0;
  auto alloc = [&](size_t bytes) -> void* {
    void* p = ws + off;
    off += (bytes + 255) & ~(size_t)255;
    return p;
  };
  bf16* attnR = (bf16*)alloc((size_t)DEPTHd * Bb * Hh * Nn * Nn * 2);
  bf16* Wt1 = (bf16*)alloc(256 * 32 * 2);
  bf16* Wt2 = (bf16*)alloc(256 * 256 * 2);
  bf16* Wt3 = (bf16*)alloc(128 * 256 * 2);
  bf16* gWt = (bf16*)alloc(32 * 128 * 2);
  float* sgW = (float*)alloc(32 * 4);
  float* bconst = (float*)alloc(32 * 4);
  bf16* Wj1 = (bf16*)alloc(256 * 96 * 2);
  bf16* Wj2 = (bf16*)alloc(256 * 256 * 2);
  bf16* Wj3 = (bf16*)alloc(128 * 256 * 2);
  bf16* Wq = (bf16*)alloc(4 * 384 * 128 * 2);
  bf16* Wp = (bf16*)alloc(4 * 128 * 128 * 2);
  bf16* Wm1 = (bf16*)alloc(4 * 128 * 128 * 2);
  bf16* Wm2 = (bf16*)alloc(4 * 128 * 128 * 2);
  bf16* Wd1 = (bf16*)alloc(256 * 128 * 2);
  bf16* Wd2 = (bf16*)alloc(512 * 256 * 2);
  bf16* Wd3 = (bf16*)alloc(128 * 512 * 2);
  float* jf = (float*)alloc((size_t)BN * 128 * 4);
  bf16* obuf = (bf16*)alloc((size_t)BN * 128 * 2);
  char* U = (char*)alloc((size_t)BN * 384 * 4);
  float* qkvb = (float*)U;
  bf16* u1 = (bf16*)U;
  bf16* u2 = (bf16*)(U + (size_t)BN * 256 * 2);

  k_prep<<<dim3(768), dim3(256), 0, stream>>>(
      re_w1, re_w2, re_w3, ln2_g, ln2_b, rconv_w, rconv_b, je_w1, je_w2, je_w3,
      qkv_w, proj_w, mw1, mw2, dw1, dw2, dw3, Wt1, Wt2, Wt3, gWt, sgW, bconst,
      Wj1, Wj2, Wj3, Wq, Wp, Wm1, Wm2, Wd1, Wd2, Wd3);

  // relation encoder (fills attnR) + joint encoder (fills jf) in one dispatch
  k_relj<<<dim3(RELB + JB), dim3(256), 0, stream>>>(
      relation_in, Wt1, re_b1, Wt2, re_b2, Wt3, re_b3, gWt, sgW, bconst, attnR,
      joint_in, Wj1, je_b1, Wj2, je_b2, Wj3, je_b3, jf);

  // depth 0 QKV
  k_lnqkv<float><<<dim3(3, 16), dim3(256), 0, stream>>>(
      jf, ln1_g, ln1_b, Wq, qkv_b, qkvb, 384, 384);

  for (int d = 0; d < DEPTHd; ++d) {
    k_attn<<<dim3(Nn, Hh, Bb), dim3(256), 0, stream>>>(
        qkvb, attnR + (size_t)d * Bb * Hh * Nn * Nn, conn, obuf);
    if (d < 3) {
      k_tailq<true><<<dim3(16), dim3(256), 0, stream>>>(
          obuf, jf, Wp + (size_t)d * 16384, proj_b + d * 128, ln3_g + d * 128,
          ln3_b + d * 128, Wm1 + (size_t)d * 16384, mb1 + d * 128,
          Wm2 + (size_t)d * 16384, mb2 + d * 128, ln1_g + (d + 1) * 128,
          ln1_b + (d + 1) * 128, Wq + (size_t)(d + 1) * 49152, qkv_b + (d + 1) * 384,
          qkvb);
    } else {
      k_tailq<false><<<dim3(16), dim3(256), 0, stream>>>(
          obuf, jf, Wp + (size_t)d * 16384, proj_b + d * 128, ln3_g + d * 128,
          ln3_b + d * 128, Wm1 + (size_t)d * 16384, mb1 + d * 128,
          Wm2 + (size_t)d * 16384, mb2 + d * 128, nullptr, nullptr, nullptr, nullptr,
          nullptr);
    }
  }

  // final LN fused into decoder layer 1; then 256 -> 512 -> 90
  k_lnqkv<bf16><<<dim3(2, 16), dim3(256), 0, stream>>>(jf, ng, nb, Wd1, db1, u1, 256,
                                                       256);
  k_gemm_mfma<bf16, bf16, false, false><<<dim3(4, 16), dim3(256), 0, stream>>>(
      u1, 256, 256, Wd2, db2, u2, 512, 512, nullptr);
  k_gemm_mfma<bf16, float, false, false><<<dim3(1, 16), dim3(256), 0, stream>>>(
      u2, 512, 512, Wd3, db3, (float*)d_out, 90, 90, nullptr);
}

// Round 9
// 943.799 us; speedup vs baseline: 1.0794x; 1.0794x over previous
//
#include <hip/hip_runtime.h>
#include <hip/hip_bf16.h>
#include <math.h>

typedef __hip_bfloat16 bf16;
typedef __attribute__((ext_vector_type(8))) short short8;
typedef __attribute__((ext_vector_type(4))) float f32x4;

#define Bb 8
#define Nn 256
#define Hh 8
#define DEPTHd 4
#define BN 2048
#define RTOT 524288
#define RELB 8192          // RTOT/64 relation blocks
#define JB 32              // BN/64 joint blocks
#define XTS 136

// k_rel3 LDS layout (bytes)
#define A0_OFF 0           // [64][104] bf16 = 13312
#define X1S_OFF 13312      // [64][40]  bf16 = 5120
#define X2_OFF 18432       // [64][264] bf16 = 33792 (x3 [64][136] aliases)
#define BST_OFF 52224      // 16384 staging
#define SST_OFF 68608      // [64][4][2] f32 = 2048
#define SSF_OFF 70656      // [64][2] f32 = 512
#define SMEM_TOT 71168
#define A0S 104
#define X1SS 40
#define X2S 264
#define X3S 136

__device__ inline float toF(float v) { return v; }
__device__ inline float toF(bf16 v) { return __bfloat162float(v); }
__device__ inline void stF(float* p, float v) { *p = v; }
__device__ inline void stF(bf16* p, float v) { *p = __float2bfloat16(v); }

__device__ inline void gload16(const bf16* g, bf16* l) {
  __builtin_amdgcn_global_load_lds(
      (const __attribute__((address_space(1))) unsigned int*)g,
      (__attribute__((address_space(3))) unsigned int*)l, 16, 0, 0);
}

__device__ inline float blk_sum(float v, float* sred) {
#pragma unroll
  for (int off = 32; off; off >>= 1) v += __shfl_down(v, off, 64);
  int wid = threadIdx.x >> 6;
  int lane = threadIdx.x & 63;
  int nw = blockDim.x >> 6;
  if (lane == 0) sred[wid] = v;
  __syncthreads();
  float s = ((int)threadIdx.x < nw) ? sred[threadIdx.x] : 0.f;
  s += __shfl_down(s, 2, 64);
  s += __shfl_down(s, 1, 64);
  if (threadIdx.x == 0) sred[4] = s;
  __syncthreads();
  float r = sred[4];
  __syncthreads();
  return r;
}

__device__ inline float blk_max(float v, float* sred) {
#pragma unroll
  for (int off = 32; off; off >>= 1) v = fmaxf(v, __shfl_down(v, off, 64));
  int wid = threadIdx.x >> 6;
  int lane = threadIdx.x & 63;
  int nw = blockDim.x >> 6;
  if (lane == 0) sred[wid] = v;
  __syncthreads();
  float s = ((int)threadIdx.x < nw) ? sred[threadIdx.x] : -INFINITY;
  s = fmaxf(s, __shfl_down(s, 2, 64));
  s = fmaxf(s, __shfl_down(s, 1, 64));
  if (threadIdx.x == 0) sred[4] = s;
  __syncthreads();
  float r = sred[4];
  __syncthreads();
  return r;
}

// =============== k_rel3: relation encoder via LDS-staged B (m97 pattern) ===============
// 64-row blocks. L1 fused into L2 K-loop (x1 strip produced on the fly).
// B operands staged async via global_load_lds; consume/produce alternation, 2 barriers/iter.
// Blocks [0,RELB): relation -> attnR. Blocks [RELB,RELB+JB): joint encoder -> jf.
__global__ __launch_bounds__(256) void k_rel3(
    const float* __restrict__ rin, const bf16* __restrict__ Wt1,
    const float* __restrict__ b1, const bf16* __restrict__ Wt2,
    const float* __restrict__ b2, const bf16* __restrict__ Wt3,
    const float* __restrict__ b3, const bf16* __restrict__ gWt,
    const float* __restrict__ sgW, const float* __restrict__ bconst,
    bf16* __restrict__ attnR, const float* __restrict__ jin,
    const bf16* __restrict__ Wj1, const float* __restrict__ jb1,
    const bf16* __restrict__ Wj2, const float* __restrict__ jb2,
    const bf16* __restrict__ Wj3, const float* __restrict__ jb3,
    float* __restrict__ jf) {
  __shared__ __align__(16) char smem[SMEM_TOT];
  bf16* A0 = (bf16*)(smem + A0_OFF);
  bf16* x1s = (bf16*)(smem + X1S_OFF);
  bf16* x2 = (bf16*)(smem + X2_OFF);
  bf16* x3 = (bf16*)(smem + X2_OFF);  // alias (x2 dead when x3 written)
  bf16* Bst = (bf16*)(smem + BST_OFF);
  float* sstat = (float*)(smem + SST_OFF);
  float* sstatF = (float*)(smem + SSF_OFF);

  const int t = threadIdx.x;
  const int lane = t & 63, wv = t >> 6;
  const int lrow = lane & 15, quad = lane >> 4;
  const bool rel = blockIdx.x < RELB;

  const bf16* W1 = rel ? Wt1 : Wj1;
  const bf16* W2 = rel ? Wt2 : Wj2;
  const bf16* W3 = rel ? Wt3 : Wj3;
  const float* B1 = rel ? b1 : jb1;
  const float* B2v = rel ? b2 : jb2;

  // ---- stage A0 ----
  if (rel) {
    const long r0 = (long)blockIdx.x * 64;
    for (int idx = t; idx < 64 * 32; idx += 256) {
      int r = idx >> 5, k = idx & 31;
      A0[r * A0S + k] = __float2bfloat16(k < 26 ? rin[r0 * 26 + r * 26 + k] : 0.f);
    }
  } else {
    const long r0j = (long)(blockIdx.x - RELB) * 64;
    for (int idx = t; idx < 64 * 96; idx += 256) {
      int r = idx / 96, k = idx - r * 96;
      A0[r * A0S + k] = __float2bfloat16(jin[(r0j + r) * 96 + k]);
    }
  }

  // producer: stage W2 k-strip [256 cols][32] + compute x1s strip for k0
  auto produce2 = [&](int k0) {
#pragma unroll
    for (int c = 0; c < 4; ++c) {
      int cg = wv * 64 + c * 16;
      int col = cg + (lane >> 2);
      gload16(&W2[(size_t)col * 256 + k0 + (lane & 3) * 8], &Bst[cg * 32]);
    }
    // x1s strip: wave computes rows wv*16..+15, cols k0..k0+31
    f32x4 xac[2];
    {
      f32x4 z = {0.f, 0.f, 0.f, 0.f};
      xac[0] = z;
      xac[1] = z;
    }
    if (rel) {
      short8 a0 = *(const short8*)&A0[(wv * 16 + lrow) * A0S + quad * 8];
#pragma unroll
      for (int ct = 0; ct < 2; ++ct) {
        short8 bw = *(const short8*)&W1[(k0 + ct * 16 + lrow) * 32 + quad * 8];
        xac[ct] = __builtin_amdgcn_mfma_f32_16x16x32_bf16(a0, bw, xac[ct], 0, 0, 0);
      }
    } else {
#pragma unroll
      for (int ks = 0; ks < 3; ++ks) {
        short8 a0 = *(const short8*)&A0[(wv * 16 + lrow) * A0S + ks * 32 + quad * 8];
#pragma unroll
        for (int ct = 0; ct < 2; ++ct) {
          short8 bw =
              *(const short8*)&W1[(k0 + ct * 16 + lrow) * 96 + ks * 32 + quad * 8];
          xac[ct] = __builtin_amdgcn_mfma_f32_16x16x32_bf16(a0, bw, xac[ct], 0, 0, 0);
        }
      }
    }
#pragma unroll
    for (int ct = 0; ct < 2; ++ct) {
      int col = k0 + ct * 16 + lrow;
      float bv = B1[col];
#pragma unroll
      for (int r = 0; r < 4; ++r)
        x1s[(wv * 16 + quad * 4 + r) * X1SS + ct * 16 + lrow] =
            __float2bfloat16(xac[ct][r] + bv);
    }
  };

  // ---- L2 (K=256): acc2 accumulates in registers; x1 strips produced on the fly ----
  f32x4 acc2[4][4];
#pragma unroll
  for (int i = 0; i < 4; ++i)
#pragma unroll
    for (int j = 0; j < 4; ++j) {
      f32x4 z = {0.f, 0.f, 0.f, 0.f};
      acc2[i][j] = z;
    }
  __syncthreads();  // A0 staged
  produce2(0);
  __syncthreads();
  for (int k = 0; k < 8; ++k) {
    short8 af[4], bfr[4];
#pragma unroll
    for (int i = 0; i < 4; ++i)
      af[i] = *(const short8*)&x1s[(i * 16 + lrow) * X1SS + quad * 8];
#pragma unroll
    for (int j = 0; j < 4; ++j)
      bfr[j] = *(const short8*)&Bst[(wv * 64 + j * 16 + lrow) * 32 + quad * 8];
#pragma unroll
    for (int i = 0; i < 4; ++i)
#pragma unroll
      for (int j = 0; j < 4; ++j)
        acc2[i][j] =
            __builtin_amdgcn_mfma_f32_16x16x32_bf16(af[i], bfr[j], acc2[i][j], 0, 0, 0);
    __syncthreads();
    if (k < 7) {
      produce2((k + 1) * 32);
      __syncthreads();
    }
  }

  // stage W3 strip s: [128 cols][64 k] into Bst
  auto produce3 = [&](int s) {
#pragma unroll
    for (int c = 0; c < 4; ++c) {
      int cg = wv * 32 + c * 8;
      int col = cg + (lane >> 3);
      gload16(&W3[(size_t)col * 256 + s * 64 + (lane & 7) * 8], &Bst[cg * 64]);
    }
  };

  // write x2 from acc2, first W3 stage
  {
#pragma unroll
    for (int i = 0; i < 4; ++i)
#pragma unroll
      for (int j = 0; j < 4; ++j) {
        int col = wv * 64 + j * 16 + lrow;
        float bv = B2v[col];
#pragma unroll
        for (int r = 0; r < 4; ++r)
          x2[(i * 16 + quad * 4 + r) * X2S + col] = __float2bfloat16(acc2[i][j][r] + bv);
      }
    produce3(0);
  }
  __syncthreads();

  // ---- L3 (K=256, 128 cols): wave = 64 rows x 32 cols ----
  f32x4 acc3[4][2];
#pragma unroll
  for (int i = 0; i < 4; ++i) {
    f32x4 z = {0.f, 0.f, 0.f, 0.f};
    acc3[i][0] = z;
    acc3[i][1] = z;
  }
  for (int s = 0; s < 4; ++s) {
#pragma unroll
    for (int kk = 0; kk < 2; ++kk) {
      short8 af[4], bfr[2];
#pragma unroll
      for (int i = 0; i < 4; ++i)
        af[i] =
            *(const short8*)&x2[(i * 16 + lrow) * X2S + s * 64 + kk * 32 + quad * 8];
#pragma unroll
      for (int j = 0; j < 2; ++j)
        bfr[j] =
            *(const short8*)&Bst[(wv * 32 + j * 16 + lrow) * 64 + kk * 32 + quad * 8];
#pragma unroll
      for (int i = 0; i < 4; ++i)
#pragma unroll
        for (int j = 0; j < 2; ++j)
          acc3[i][j] =
              __builtin_amdgcn_mfma_f32_16x16x32_bf16(af[i], bfr[j], acc3[i][j], 0, 0, 0);
    }
    __syncthreads();
    if (s < 3) {
      produce3(s + 1);
      __syncthreads();
    }
  }

  if (!rel) {
    const long r0j = (long)(blockIdx.x - RELB) * 64;
#pragma unroll
    for (int i = 0; i < 4; ++i)
#pragma unroll
      for (int j = 0; j < 2; ++j) {
        int col = wv * 32 + j * 16 + lrow;
        float bv = jb3[col];
#pragma unroll
        for (int r = 0; r < 4; ++r)
          jf[(r0j + i * 16 + quad * 4 + r) * 128 + col] = acc3[i][j][r] + bv;
      }
    return;
  }

  // ---- rel: x3 write (alias x2) + LN stats ----
#pragma unroll
  for (int i = 0; i < 4; ++i) {
#pragma unroll
    for (int r = 0; r < 4; ++r) {
      int row = i * 16 + quad * 4 + r;
      float v0 = acc3[i][0][r] + b3[wv * 32 + lrow];
      float v1 = acc3[i][1][r] + b3[wv * 32 + 16 + lrow];
      x3[row * X3S + wv * 32 + lrow] = __float2bfloat16(v0);
      x3[row * X3S + wv * 32 + 16 + lrow] = __float2bfloat16(v1);
      float s1 = v0 + v1, s2 = v0 * v0 + v1 * v1;
#pragma unroll
      for (int m = 1; m < 16; m <<= 1) {
        s1 += __shfl_xor(s1, m, 64);
        s2 += __shfl_xor(s2, m, 64);
      }
      if (lrow == 0) {
        sstat[(row * 4 + wv) * 2] = s1;
        sstat[(row * 4 + wv) * 2 + 1] = s2;
      }
    }
  }
  // hoist gemm32 A-operands (gWt, L1/L2-hot) across stats barriers
  short8 aw0[4], aw1[4];
#pragma unroll
  for (int kk = 0; kk < 4; ++kk) {
    aw0[kk] = *(const short8*)&gWt[lrow * 128 + kk * 32 + quad * 8];
    aw1[kk] = *(const short8*)&gWt[(16 + lrow) * 128 + kk * 32 + quad * 8];
  }
  __syncthreads();
  if (t < 64) {
    float s1 = 0.f, s2 = 0.f;
#pragma unroll
    for (int w = 0; w < 4; ++w) {
      s1 += sstat[(t * 4 + w) * 2];
      s2 += sstat[(t * 4 + w) * 2 + 1];
    }
    float mu = s1 * (1.f / 128.f);
    float var = s2 * (1.f / 128.f) - mu * mu;
    sstatF[t * 2] = mu;
    sstatF[t * 2 + 1] = rsqrtf(var + 1e-5f);
  }
  __syncthreads();

  // ---- gemm32: 32 out-chans x 64 rows (wave = 16 rows), LN stats trick, scatter ----
  {
    f32x4 ac0 = {0.f, 0.f, 0.f, 0.f}, ac1 = {0.f, 0.f, 0.f, 0.f};
#pragma unroll
    for (int kk = 0; kk < 4; ++kk) {
      short8 bbx = *(const short8*)&x3[(wv * 16 + lrow) * X3S + kk * 32 + quad * 8];
      ac0 = __builtin_amdgcn_mfma_f32_16x16x32_bf16(aw0[kk], bbx, ac0, 0, 0, 0);
      ac1 = __builtin_amdgcn_mfma_f32_16x16x32_bf16(aw1[kk], bbx, ac1, 0, 0, 0);
    }
    const long r0 = (long)blockIdx.x * 64;
    int drow = wv * 16 + lrow;
    long gr = r0 + drow;
    float mu = sstatF[drow * 2], inv = sstatF[drow * 2 + 1];
    int bb_ = (int)(gr >> 16);
    int nn = (int)((gr >> 8) & 255);
    int mm = (int)(gr & 255);
#pragma unroll
    for (int mt = 0; mt < 2; ++mt) {
      f32x4 a = mt ? ac1 : ac0;
#pragma unroll
      for (int reg = 0; reg < 4; ++reg) {
        int col = mt * 16 + quad * 4 + reg;
        float v = inv * (a[reg] - mu * sgW[col]) + bconst[col];
        int dd = col >> 3, hh = col & 7;
        attnR[((((long)dd * Bb + bb_) * Hh + hh) * Nn + nn) * Nn + mm] =
            __float2bfloat16(v);
      }
    }
  }
}

// =============== MFMA GEMM (generic, LDS-staged): decoder 2/3 ===============
template <typename TA, typename TC, bool GELU, bool RESID>
__global__ __launch_bounds__(256) void k_gemm_mfma(
    const TA* __restrict__ A, int Ka, int Kp, const bf16* __restrict__ Bt,
    const float* __restrict__ bias, TC* __restrict__ C, int ldc, int ncols,
    const float* __restrict__ resid) {
  __shared__ __align__(16) bf16 sA[128 * 32];
  __shared__ __align__(16) bf16 sB[128 * 32];
  const int t = threadIdx.x;
  const int lane = t & 63;
  const int wv = t >> 6;
  const int wr = wv >> 1, wc = wv & 1;
  const int lrow = lane & 15, quad = lane >> 4;
  const long row0 = (long)blockIdx.y * 128;
  const int n0 = blockIdx.x * 128;
  const int rg = lane >> 2;
  const int kE = (lane & 3) * 8;

  f32x4 zero = {0.f, 0.f, 0.f, 0.f};
  f32x4 acc[4][4];
#pragma unroll
  for (int i = 0; i < 4; ++i)
#pragma unroll
    for (int j = 0; j < 4; ++j) acc[i][j] = zero;

  for (int k0 = 0; k0 < Kp; k0 += 32) {
    {
      const int r0 = wv * 32;
      gload16(&Bt[(long)(n0 + r0 + rg) * Kp + k0 + kE], &sB[r0 * 32]);
      gload16(&Bt[(long)(n0 + r0 + 16 + rg) * Kp + k0 + kE], &sB[(r0 + 16) * 32]);
    }
    if (sizeof(TA) == 2) {
      const int r0 = wv * 32;
      gload16((const bf16*)&A[(row0 + r0 + rg) * (long)Ka + k0 + kE], &sA[r0 * 32]);
      gload16((const bf16*)&A[(row0 + r0 + 16 + rg) * (long)Ka + k0 + kE],
              &sA[(r0 + 16) * 32]);
    } else {
      for (int idx = t; idx < 128 * 32; idx += 256) {
        int r = idx >> 5, k = idx & 31;
        int gk = k0 + k;
        float v = (gk < Ka) ? toF(A[(row0 + r) * (long)Ka + gk]) : 0.f;
        sA[idx] = __float2bfloat16(v);
      }
    }
    __syncthreads();
    short8 af[4], bfr[4];
#pragma unroll
    for (int i = 0; i < 4; ++i)
      af[i] = *(const short8*)&sA[(wr * 64 + i * 16 + lrow) * 32 + quad * 8];
#pragma unroll
    for (int j = 0; j < 4; ++j)
      bfr[j] = *(const short8*)&sB[(wc * 64 + j * 16 + lrow) * 32 + quad * 8];
#pragma unroll
    for (int i = 0; i < 4; ++i)
#pragma unroll
      for (int j = 0; j < 4; ++j)
        acc[i][j] =
            __builtin_amdgcn_mfma_f32_16x16x32_bf16(af[i], bfr[j], acc[i][j], 0, 0, 0);
    __syncthreads();
  }

#pragma unroll
  for (int i = 0; i < 4; ++i) {
#pragma unroll
    for (int r = 0; r < 4; ++r) {
      int rl = wr * 64 + i * 16 + quad * 4 + r;
      long gr = row0 + rl;
#pragma unroll
      for (int j = 0; j < 4; ++j) {
        int gc = n0 + wc * 64 + j * 16 + lrow;
        if (gc < ncols) {
          float v = acc[i][j][r] + bias[gc];
          if (GELU) v = 0.5f * v * (1.f + erff(v * 0.70710678118654752f));
          if (RESID) v += resid[gr * (long)ldc + gc];
          stF(&C[gr * (long)ldc + gc], v);
        }
      }
    }
  }
}

// =============== k_lnqkv: row-LN (dim 128) fused into K=128 GEMM ===============
template <typename TC>
__global__ __launch_bounds__(256) void k_lnqkv(
    const float* __restrict__ A, const float* __restrict__ g,
    const float* __restrict__ b, const bf16* __restrict__ Bt,
    const float* __restrict__ bias, TC* __restrict__ C, int ldc, int ncols) {
  __shared__ __align__(16) bf16 sX[128 * XTS];
  const int t = threadIdx.x;
  const int lane = t & 63;
  const int wv = t >> 6;
  const int wr = wv >> 1, wc = wv & 1;
  const int lrow = lane & 15, quad = lane >> 4;
  const long row0 = (long)blockIdx.y * 128;
  const int n0 = blockIdx.x * 128;

  {
    int row = t >> 1, half = t & 1;
    const float* ap = &A[(row0 + row) * 128 + half * 64];
    float v[64];
    float s1 = 0.f, s2 = 0.f;
#pragma unroll
    for (int u = 0; u < 16; ++u) {
      f32x4 q = *(const f32x4*)(ap + u * 4);
#pragma unroll
      for (int e = 0; e < 4; ++e) {
        v[u * 4 + e] = q[e];
        s1 += q[e];
        s2 += q[e] * q[e];
      }
    }
    s1 += __shfl_xor(s1, 1, 64);
    s2 += __shfl_xor(s2, 1, 64);
    float mu = s1 * (1.f / 128.f);
    float inv = rsqrtf(s2 * (1.f / 128.f) - mu * mu + 1e-5f);
#pragma unroll
    for (int u = 0; u < 64; ++u) {
      int c = half * 64 + u;
      sX[row * XTS + c] = __float2bfloat16((v[u] - mu) * inv * g[c] + b[c]);
    }
  }
  __syncthreads();

  f32x4 acc[4][4];
#pragma unroll
  for (int i = 0; i < 4; ++i)
#pragma unroll
    for (int j = 0; j < 4; ++j) {
      f32x4 z = {0.f, 0.f, 0.f, 0.f};
      acc[i][j] = z;
    }
#pragma unroll
  for (int k0 = 0; k0 < 128; k0 += 32) {
    short8 af[4], bfr[4];
#pragma unroll
    for (int j = 0; j < 4; ++j)
      bfr[j] = *(const short8*)&Bt[(long)(n0 + wc * 64 + j * 16 + lrow) * 128 + k0 +
                                   quad * 8];
#pragma unroll
    for (int i = 0; i < 4; ++i)
      af[i] = *(const short8*)&sX[(wr * 64 + i * 16 + lrow) * XTS + k0 + quad * 8];
#pragma unroll
    for (int i = 0; i < 4; ++i)
#pragma unroll
      for (int j = 0; j < 4; ++j)
        acc[i][j] =
            __builtin_amdgcn_mfma_f32_16x16x32_bf16(af[i], bfr[j], acc[i][j], 0, 0, 0);
  }
#pragma unroll
  for (int i = 0; i < 4; ++i) {
#pragma unroll
    for (int r = 0; r < 4; ++r) {
      long gr = row0 + wr * 64 + i * 16 + quad * 4 + r;
#pragma unroll
      for (int j = 0; j < 4; ++j) {
        int gc = n0 + wc * 64 + j * 16 + lrow;
        if (gc < ncols) stF(&C[gr * (long)ldc + gc], acc[i][j][r] + bias[gc]);
      }
    }
  }
}

// =============== k_tailq: proj+resid -> LN3 -> MLP(+gelu) -> resid [-> LN1' + QKV'] ===============
template <bool QKV>
__global__ __launch_bounds__(256) void k_tailq(
    const bf16* __restrict__ obuf, float* __restrict__ jf, const bf16* __restrict__ Wp,
    const float* __restrict__ pb, const float* __restrict__ g3,
    const float* __restrict__ b3, const bf16* __restrict__ Wm1,
    const float* __restrict__ m1b, const bf16* __restrict__ Wm2,
    const float* __restrict__ m2b, const float* __restrict__ g1n,
    const float* __restrict__ b1n, const bf16* __restrict__ Wqn,
    const float* __restrict__ qbn, float* __restrict__ qkvb) {
  __shared__ __align__(16) bf16 sX[128 * XTS];
  __shared__ __align__(16) bf16 sH[128 * XTS];
  __shared__ float sstat[128][2][2];
  __shared__ float sstatF[128][2];

  const int t = threadIdx.x;
  const int lane = t & 63;
  const int wv = t >> 6;
  const int wr = wv >> 1, wc = wv & 1;
  const int lrow = lane & 15, quad = lane >> 4;
  const long row0 = (long)blockIdx.x * 128;

#pragma unroll
  for (int u = 0; u < 8; ++u) {
    int idx = t + u * 256;
    int r = idx >> 4, c8 = (idx & 15) * 8;
    *(uint4*)&sX[r * XTS + c8] = *(const uint4*)&obuf[(row0 + r) * 128 + c8];
  }
  __syncthreads();

  f32x4 acc[4][4];
#pragma unroll
  for (int i = 0; i < 4; ++i)
#pragma unroll
    for (int j = 0; j < 4; ++j) {
      f32x4 z = {0.f, 0.f, 0.f, 0.f};
      acc[i][j] = z;
    }
#pragma unroll
  for (int k0 = 0; k0 < 128; k0 += 32) {
    short8 af[4], bfr[4];
#pragma unroll
    for (int i = 0; i < 4; ++i)
      af[i] = *(const short8*)&sX[(wr * 64 + i * 16 + lrow) * XTS + k0 + quad * 8];
#pragma unroll
    for (int j = 0; j < 4; ++j)
      bfr[j] = *(const short8*)&Wp[(wc * 64 + j * 16 + lrow) * 128 + k0 + quad * 8];
#pragma unroll
    for (int i = 0; i < 4; ++i)
#pragma unroll
      for (int j = 0; j < 4; ++j)
        acc[i][j] =
            __builtin_amdgcn_mfma_f32_16x16x32_bf16(af[i], bfr[j], acc[i][j], 0, 0, 0);
  }
#pragma unroll
  for (int i = 0; i < 4; ++i) {
#pragma unroll
    for (int r = 0; r < 4; ++r) {
      int rl = wr * 64 + i * 16 + quad * 4 + r;
      long gr = row0 + rl;
      float s1 = 0.f, s2 = 0.f;
#pragma unroll
      for (int j = 0; j < 4; ++j) {
        int gc = wc * 64 + j * 16 + lrow;
        float v = acc[i][j][r] + pb[gc] + jf[gr * 128 + gc];
        acc[i][j][r] = v;
        jf[gr * 128 + gc] = v;
        s1 += v;
        s2 += v * v;
      }
#pragma unroll
      for (int m = 1; m < 16; m <<= 1) {
        s1 += __shfl_xor(s1, m, 64);
        s2 += __shfl_xor(s2, m, 64);
      }
      if (lrow == 0) {
        sstat[rl][wc][0] = s1;
        sstat[rl][wc][1] = s2;
      }
    }
  }
  __syncthreads();
  if (t < 128) {
    float s1 = sstat[t][0][0] + sstat[t][1][0];
    float s2 = sstat[t][0][1] + sstat[t][1][1];
    float mu = s1 * (1.f / 128.f);
    float var = s2 * (1.f / 128.f) - mu * mu;
    sstatF[t][0] = mu;
    sstatF[t][1] = rsqrtf(var + 1e-5f);
  }
  __syncthreads();
#pragma unroll
  for (int i = 0; i < 4; ++i) {
#pragma unroll
    for (int r = 0; r < 4; ++r) {
      int rl = wr * 64 + i * 16 + quad * 4 + r;
      float mu = sstatF[rl][0], inv = sstatF[rl][1];
#pragma unroll
      for (int j = 0; j < 4; ++j) {
        int gc = wc * 64 + j * 16 + lrow;
        sX[rl * XTS + gc] = __float2bfloat16((acc[i][j][r] - mu) * inv * g3[gc] + b3[gc]);
      }
    }
  }
  __syncthreads();

  f32x4 acc2[4][4];
#pragma unroll
  for (int i = 0; i < 4; ++i)
#pragma unroll
    for (int j = 0; j < 4; ++j) {
      f32x4 z = {0.f, 0.f, 0.f, 0.f};
      acc2[i][j] = z;
    }
#pragma unroll
  for (int k0 = 0; k0 < 128; k0 += 32) {
    short8 af[4], bfr[4];
#pragma unroll
    for (int i = 0; i < 4; ++i)
      af[i] = *(const short8*)&sX[(wr * 64 + i * 16 + lrow) * XTS + k0 + quad * 8];
#pragma unroll
    for (int j = 0; j < 4; ++j)
      bfr[j] = *(const short8*)&Wm1[(wc * 64 + j * 16 + lrow) * 128 + k0 + quad * 8];
#pragma unroll
    for (int i = 0; i < 4; ++i)
#pragma unroll
      for (int j = 0; j < 4; ++j)
        acc2[i][j] =
            __builtin_amdgcn_mfma_f32_16x16x32_bf16(af[i], bfr[j], acc2[i][j], 0, 0, 0);
  }
#pragma unroll
  for (int i = 0; i < 4; ++i) {
#pragma unroll
    for (int r = 0; r < 4; ++r) {
      int rl = wr * 64 + i * 16 + quad * 4 + r;
#pragma unroll
      for (int j = 0; j < 4; ++j) {
        int gc = wc * 64 + j * 16 + lrow;
        float v = acc2[i][j][r] + m1b[gc];
        v = 0.5f * v * (1.f + erff(v * 0.70710678118654752f));
        sH[rl * XTS + gc] = __float2bfloat16(v);
      }
    }
  }
  __syncthreads();

  f32x4 acc3[4][4];
#pragma unroll
  for (int i = 0; i < 4; ++i)
#pragma unroll
    for (int j = 0; j < 4; ++j) {
      f32x4 z = {0.f, 0.f, 0.f, 0.f};
      acc3[i][j] = z;
    }
#pragma unroll
  for (int k0 = 0; k0 < 128; k0 += 32) {
    short8 af[4], bfr[4];
#pragma unroll
    for (int i = 0; i < 4; ++i)
      af[i] = *(const short8*)&sH[(wr * 64 + i * 16 + lrow) * XTS + k0 + quad * 8];
#pragma unroll
    for (int j = 0; j < 4; ++j)
      bfr[j] = *(const short8*)&Wm2[(wc * 64 + j * 16 + lrow) * 128 + k0 + quad * 8];
#pragma unroll
    for (int i = 0; i < 4; ++i)
#pragma unroll
      for (int j = 0; j < 4; ++j)
        acc3[i][j] =
            __builtin_amdgcn_mfma_f32_16x16x32_bf16(af[i], bfr[j], acc3[i][j], 0, 0, 0);
  }
#pragma unroll
  for (int i = 0; i < 4; ++i) {
#pragma unroll
    for (int r = 0; r < 4; ++r) {
      int rl = wr * 64 + i * 16 + quad * 4 + r;
      long gr = row0 + rl;
      float s1 = 0.f, s2 = 0.f;
#pragma unroll
      for (int j = 0; j < 4; ++j) {
        int gc = wc * 64 + j * 16 + lrow;
        float v = acc3[i][j][r] + m2b[gc] + jf[gr * 128 + gc];
        acc3[i][j][r] = v;
        jf[gr * 128 + gc] = v;
        if (QKV) {
          s1 += v;
          s2 += v * v;
        }
      }
      if (QKV) {
#pragma unroll
        for (int m = 1; m < 16; m <<= 1) {
          s1 += __shfl_xor(s1, m, 64);
          s2 += __shfl_xor(s2, m, 64);
        }
        if (lrow == 0) {
          sstat[rl][wc][0] = s1;
          sstat[rl][wc][1] = s2;
        }
      }
    }
  }
  if (!QKV) return;
  __syncthreads();
  if (t < 128) {
    float s1 = sstat[t][0][0] + sstat[t][1][0];
    float s2 = sstat[t][0][1] + sstat[t][1][1];
    float mu = s1 * (1.f / 128.f);
    float var = s2 * (1.f / 128.f) - mu * mu;
    sstatF[t][0] = mu;
    sstatF[t][1] = rsqrtf(var + 1e-5f);
  }
  __syncthreads();
#pragma unroll
  for (int i = 0; i < 4; ++i) {
#pragma unroll
    for (int r = 0; r < 4; ++r) {
      int rl = wr * 64 + i * 16 + quad * 4 + r;
      float mu = sstatF[rl][0], inv = sstatF[rl][1];
#pragma unroll
      for (int j = 0; j < 4; ++j) {
        int gc = wc * 64 + j * 16 + lrow;
        sX[rl * XTS + gc] =
            __float2bfloat16((acc3[i][j][r] - mu) * inv * g1n[gc] + b1n[gc]);
      }
    }
  }
  __syncthreads();
  for (int p = 0; p < 3; ++p) {
    f32x4 acc4[4][4];
#pragma unroll
    for (int i = 0; i < 4; ++i)
#pragma unroll
      for (int j = 0; j < 4; ++j) {
        f32x4 z = {0.f, 0.f, 0.f, 0.f};
        acc4[i][j] = z;
      }
#pragma unroll
    for (int k0 = 0; k0 < 128; k0 += 32) {
      short8 af[4], bfr[4];
#pragma unroll
      for (int i = 0; i < 4; ++i)
        af[i] = *(const short8*)&sX[(wr * 64 + i * 16 + lrow) * XTS + k0 + quad * 8];
#pragma unroll
      for (int j = 0; j < 4; ++j)
        bfr[j] = *(const short8*)&Wqn[(long)(p * 128 + wc * 64 + j * 16 + lrow) * 128 +
                                      k0 + quad * 8];
#pragma unroll
      for (int i = 0; i < 4; ++i)
#pragma unroll
        for (int j = 0; j < 4; ++j)
          acc4[i][j] =
              __builtin_amdgcn_mfma_f32_16x16x32_bf16(af[i], bfr[j], acc4[i][j], 0, 0, 0);
    }
#pragma unroll
    for (int i = 0; i < 4; ++i) {
#pragma unroll
      for (int r = 0; r < 4; ++r) {
        long gr = row0 + wr * 64 + i * 16 + quad * 4 + r;
#pragma unroll
        for (int j = 0; j < 4; ++j) {
          int gc = p * 128 + wc * 64 + j * 16 + lrow;
          qkvb[gr * 384 + gc] = acc4[i][j][r] + qbn[gc];
        }
      }
    }
  }
}

// ---- prep: transpose+cast all weights to bf16 [col][K]; build gW / sgW / bconst ----
__global__ void k_prep(const float* re_w1, const float* re_w2, const float* re_w3,
                       const float* ln2_g, const float* ln2_b, const float* rconv_w,
                       const float* rconv_b, const float* je_w1, const float* je_w2,
                       const float* je_w3, const float* qkv_w, const float* proj_w,
                       const float* mw1, const float* mw2, const float* dw1,
                       const float* dw2, const float* dw3, bf16* Wt1, bf16* Wt2,
                       bf16* Wt3, bf16* gWt, float* sgW, float* bconst, bf16* Wj1,
                       bf16* Wj2, bf16* Wj3, bf16* Wq, bf16* Wp, bf16* Wm1, bf16* Wm2,
                       bf16* Wd1, bf16* Wd2, bf16* Wd3) {
  const int stride = gridDim.x * blockDim.x;
  const int tid = blockIdx.x * blockDim.x + threadIdx.x;
  for (int i = tid; i < 256 * 32; i += stride) {
    int n = i >> 5, k = i & 31;
    Wt1[i] = __float2bfloat16(k < 26 ? re_w1[k * 256 + n] : 0.f);
  }
  for (int i = tid; i < 256 * 256; i += stride) {
    int n = i >> 8, k = i & 255;
    Wt2[i] = __float2bfloat16(re_w2[k * 256 + n]);
  }
  for (int i = tid; i < 128 * 256; i += stride) {
    int n = i >> 8, k = i & 255;
    Wt3[i] = __float2bfloat16(re_w3[k * 128 + n]);
  }
  for (int i = tid; i < 32 * 128; i += stride) {
    int col = i >> 7, c = i & 127;
    int dd = col >> 3, h = col & 7;
    gWt[i] = __float2bfloat16(ln2_g[dd * 128 + c] * rconv_w[(dd * 128 + c) * 8 + h]);
  }
  if (tid < 32) {
    int dd = tid >> 3, h = tid & 7;
    float sg = 0.f, bc = 0.f;
    for (int c = 0; c < 128; ++c) {
      float w = rconv_w[(dd * 128 + c) * 8 + h];
      sg += ln2_g[dd * 128 + c] * w;
      bc += ln2_b[dd * 128 + c] * w;
    }
    sgW[tid] = sg;
    bconst[tid] = bc + rconv_b[tid];
  }
  for (int i = tid; i < 256 * 96; i += stride) {
    int n = i / 96, k = i - n * 96;
    Wj1[i] = __float2bfloat16(je_w1[k * 256 + n]);
  }
  for (int i = tid; i < 256 * 256; i += stride) {
    int n = i >> 8, k = i & 255;
    Wj2[i] = __float2bfloat16(je_w2[k * 256 + n]);
  }
  for (int i = tid; i < 128 * 256; i += stride) {
    int n = i >> 8, k = i & 255;
    Wj3[i] = __float2bfloat16(je_w3[k * 128 + n]);
  }
  for (int i = tid; i < 4 * 384 * 128; i += stride) {
    int d = i / 49152, rem = i - d * 49152;
    int n = rem >> 7, k = rem & 127;
    Wq[i] = __float2bfloat16(qkv_w[d * 49152 + k * 384 + n]);
  }
  for (int i = tid; i < 4 * 128 * 128; i += stride) {
    int d = i >> 14, rem = i & 16383;
    int n = rem >> 7, k = rem & 127;
    Wp[i] = __float2bfloat16(proj_w[d * 16384 + k * 128 + n]);
    Wm1[i] = __float2bfloat16(mw1[d * 16384 + k * 128 + n]);
    Wm2[i] = __float2bfloat16(mw2[d * 16384 + k * 128 + n]);
  }
  for (int i = tid; i < 256 * 128; i += stride) {
    int n = i >> 7, k = i & 127;
    Wd1[i] = __float2bfloat16(dw1[k * 256 + n]);
  }
  for (int i = tid; i < 512 * 256; i += stride) {
    int n = i >> 8, k = i & 255;
    Wd2[i] = __float2bfloat16(dw2[k * 512 + n]);
  }
  for (int i = tid; i < 128 * 512; i += stride) {
    int n = i >> 9, k = i & 511;
    Wd3[i] = __float2bfloat16(n < 90 ? dw3[k * 90 + n] : 0.f);
  }
}

// ---- fused attention: logits + conn + softmax + AV ----
__global__ void k_attn(const float* __restrict__ qkv, const bf16* __restrict__ aR,
                       const float* __restrict__ conn, bf16* __restrict__ obuf) {
  __shared__ float q[16];
  __shared__ float p[256];
  __shared__ float sred[8];
  __shared__ float pv[16][17];
  int n = blockIdx.x, h = blockIdx.y, b = blockIdx.z;
  int t = threadIdx.x;
  if (t < 16) q[t] = qkv[((long)(b * Nn + n)) * 384 + h * 16 + t];
  __syncthreads();
  const float* kp = &qkv[((long)(b * Nn + t)) * 384 + 128 + h * 16];
  float lg = 0.f;
#pragma unroll
  for (int e = 0; e < 16; ++e) lg += q[e] * kp[e];
  lg += toF(aR[(((long)(b * Hh + h) * Nn + n)) * Nn + t]);
  lg = lg * conn[((long)(b * Nn + n)) * Nn + t] * 0.25f;
  float mx = blk_max(lg, sred);
  float ex = expf(lg - mx);
  float s = blk_sum(ex, sred);
  p[t] = ex / s;
  __syncthreads();
  int g = t >> 4, e = t & 15;
  const float* vp = &qkv[((long)(b * Nn + g * 16)) * 384 + 256 + h * 16 + e];
  float acc = 0.f;
#pragma unroll
  for (int mi = 0; mi < 16; ++mi) acc += p[g * 16 + mi] * vp[(long)mi * 384];
  pv[g][e] = acc;
  __syncthreads();
  if (t < 16) {
    float s2 = 0.f;
#pragma unroll
    for (int gg = 0; gg < 16; ++gg) s2 += pv[gg][t];
    obuf[((long)(b * Nn + n)) * 128 + h * 16 + t] = __float2bfloat16(s2);
  }
}

extern "C" void kernel_launch(void* const* d_in, const int* in_sizes, int n_in,
                              void* d_out, int out_size, void* d_ws, size_t ws_size,
                              hipStream_t stream) {
  const float* joint_in = (const float*)d_in[0];
  const float* relation_in = (const float*)d_in[1];
  const float* conn = (const float*)d_in[2];
  const float* je_w1 = (const float*)d_in[3];
  const float* je_b1 = (const float*)d_in[4];
  const float* je_w2 = (const float*)d_in[5];
  const float* je_b2 = (const float*)d_in[6];
  const float* je_w3 = (const float*)d_in[7];
  const float* je_b3 = (const float*)d_in[8];
  const float* re_w1 = (const float*)d_in[9];
  const float* re_b1 = (const float*)d_in[10];
  const float* re_w2 = (const float*)d_in[11];
  const float* re_b2 = (const float*)d_in[12];
  const float* re_w3 = (const float*)d_in[13];
  const float* re_b3 = (const float*)d_in[14];
  const float* qkv_w = (const float*)d_in[15];
  const float* qkv_b = (const float*)d_in[16];
  const float* rconv_w = (const float*)d_in[17];
  const float* rconv_b = (const float*)d_in[18];
  const float* proj_w = (const float*)d_in[19];
  const float* proj_b = (const float*)d_in[20];
  const float* ln1_g = (const float*)d_in[21];
  const float* ln1_b = (const float*)d_in[22];
  const float* ln2_g = (const float*)d_in[23];
  const float* ln2_b = (const float*)d_in[24];
  const float* ln3_g = (const float*)d_in[25];
  const float* ln3_b = (const float*)d_in[26];
  const float* mw1 = (const float*)d_in[27];
  const float* mb1 = (const float*)d_in[28];
  const float* mw2 = (const float*)d_in[29];
  const float* mb2 = (const float*)d_in[30];
  const float* ng = (const float*)d_in[31];
  const float* nb = (const float*)d_in[32];
  const float* dw1 = (const float*)d_in[33];
  const float* db1 = (const float*)d_in[34];
  const float* dw2 = (const float*)d_in[35];
  const float* db2 = (const float*)d_in[36];
  const float* dw3 = (const float*)d_in[37];
  const float* db3 = (const float*)d_in[38];

  char* ws = (char*)d_ws;
  size_t off = 0;
  auto alloc = [&](size_t bytes) -> void* {
    void* p = ws + off;
    off += (bytes + 255) & ~(size_t)255;
    return p;
  };
  bf16* attnR = (bf16*)alloc((size_t)DEPTHd * Bb * Hh * Nn * Nn * 2);
  bf16* Wt1 = (bf16*)alloc(256 * 32 * 2);
  bf16* Wt2 = (bf16*)alloc(256 * 256 * 2);
  bf16* Wt3 = (bf16*)alloc(128 * 256 * 2);
  bf16* gWt = (bf16*)alloc(32 * 128 * 2);
  float* sgW = (float*)alloc(32 * 4);
  float* bconst = (float*)alloc(32 * 4);
  bf16* Wj1 = (bf16*)alloc(256 * 96 * 2);
  bf16* Wj2 = (bf16*)alloc(256 * 256 * 2);
  bf16* Wj3 = (bf16*)alloc(128 * 256 * 2);
  bf16* Wq = (bf16*)alloc(4 * 384 * 128 * 2);
  bf16* Wp = (bf16*)alloc(4 * 128 * 128 * 2);
  bf16* Wm1 = (bf16*)alloc(4 * 128 * 128 * 2);
  bf16* Wm2 = (bf16*)alloc(4 * 128 * 128 * 2);
  bf16* Wd1 = (bf16*)alloc(256 * 128 * 2);
  bf16* Wd2 = (bf16*)alloc(512 * 256 * 2);
  bf16* Wd3 = (bf16*)alloc(128 * 512 * 2);
  float* jf = (float*)alloc((size_t)BN * 128 * 4);
  bf16* obuf = (bf16*)alloc((size_t)BN * 128 * 2);
  char* U = (char*)alloc((size_t)BN * 384 * 4);
  float* qkvb = (float*)U;
  bf16* u1 = (bf16*)U;
  bf16* u2 = (bf16*)(U + (size_t)BN * 256 * 2);

  k_prep<<<dim3(768), dim3(256), 0, stream>>>(
      re_w1, re_w2, re_w3, ln2_g, ln2_b, rconv_w, rconv_b, je_w1, je_w2, je_w3,
      qkv_w, proj_w, mw1, mw2, dw1, dw2, dw3, Wt1, Wt2, Wt3, gWt, sgW, bconst,
      Wj1, Wj2, Wj3, Wq, Wp, Wm1, Wm2, Wd1, Wd2, Wd3);

  // relation encoder (fills attnR) + joint encoder (fills jf)
  k_rel3<<<dim3(RELB + JB), dim3(256), 0, stream>>>(
      relation_in, Wt1, re_b1, Wt2, re_b2, Wt3, re_b3, gWt, sgW, bconst, attnR,
      joint_in, Wj1, je_b1, Wj2, je_b2, Wj3, je_b3, jf);

  // depth 0 QKV
  k_lnqkv<float><<<dim3(3, 16), dim3(256), 0, stream>>>(
      jf, ln1_g, ln1_b, Wq, qkv_b, qkvb, 384, 384);

  for (int d = 0; d < DEPTHd; ++d) {
    k_attn<<<dim3(Nn, Hh, Bb), dim3(256), 0, stream>>>(
        qkvb, attnR + (size_t)d * Bb * Hh * Nn * Nn, conn, obuf);
    if (d < 3) {
      k_tailq<true><<<dim3(16), dim3(256), 0, stream>>>(
          obuf, jf, Wp + (size_t)d * 16384, proj_b + d * 128, ln3_g + d * 128,
          ln3_b + d * 128, Wm1 + (size_t)d * 16384, mb1 + d * 128,
          Wm2 + (size_t)d * 16384, mb2 + d * 128, ln1_g + (d + 1) * 128,
          ln1_b + (d + 1) * 128, Wq + (size_t)(d + 1) * 49152, qkv_b + (d + 1) * 384,
          qkvb);
    } else {
      k_tailq<false><<<dim3(16), dim3(256), 0, stream>>>(
          obuf, jf, Wp + (size_t)d * 16384, proj_b + d * 128, ln3_g + d * 128,
          ln3_b + d * 128, Wm1 + (size_t)d * 16384, mb1 + d * 128,
          Wm2 + (size_t)d * 16384, mb2 + d * 128, nullptr, nullptr, nullptr, nullptr,
          nullptr);
    }
  }

  // final LN fused into decoder layer 1; then 256 -> 512 -> 90
  k_lnqkv<bf16><<<dim3(2, 16), dim3(256), 0, stream>>>(jf, ng, nb, Wd1, db1, u1, 256,
                                                       256);
  k_gemm_mfma<bf16, bf16, false, false><<<dim3(4, 16), dim3(256), 0, stream>>>(
      u1, 256, 256, Wd2, db2, u2, 512, 512, nullptr);
  k_gemm_mfma<bf16, float, false, false><<<dim3(1, 16), dim3(256), 0, stream>>>(
      u2, 512, 512, Wd3, db3, (float*)d_out, 90, 90, nullptr);
}